// Round 12
// baseline (368.705 us; speedup 1.0000x reference)
//
#include <hip/hip_runtime.h>
#include <math.h>

// VQVAE forward — R12: R11 with ONE change: __launch_bounds__(256,3) (was 4).
// R11 post-mortem: bound=4 squeezed VGPR 84->64 -> scratch spills (WRITE_SIZE
// 10->51 MB, FETCH 7->20 MB) that ate the occupancy gain (mega 270->313).
// The LDS diet (38912 B x 4 = 155.6 KB <= 160 KB) already permits 4 blocks/CU
// by LDS; with bound=3 the compiler's no-spill 84-VGPR codegen (<=128) lets
// the hardware reach 4 blocks/CU without forcing spills.
// Numerics identical: fp16 split-2 enc+VQ (zero argmin flips R4-R11), plain
// fp16 dec; absmax stable 0.015625.

namespace {

constexpr int kN = 262144;

typedef _Float16 half8 __attribute__((ext_vector_type(8)));
typedef float floatx4 __attribute__((ext_vector_type(4)));

#define MFMA16(a, b, c) __builtin_amdgcn_mfma_f32_16x16x32_f16((a), (b), (c), 0, 0, 0)

// ---- workspace byte offsets (weights region, as R4-R11)
constexpr size_t W1M_O = 0;        // ew1 padded [256][32] f16 (k>=9 zero), main
constexpr size_t W1R_O = 16384;    // residual
constexpr size_t E2M_O = 32768;    // ew2 [128][256]
constexpr size_t E2R_O = 98304;
constexpr size_t E3M_O = 163840;   // ew3 [64][128]
constexpr size_t E3R_O = 180224;
constexpr size_t CBM_O = 196608;   // codebook [1024][64]
constexpr size_t CBR_O = 327680;
constexpr size_t D1P_O = 458752;   // dw1 [128][64] plain
constexpr size_t D2P_O = 475136;   // dw2 [256][128] plain
constexpr size_t D3P_O = 540672;   // dw3 padded [16][256] plain
constexpr size_t CN_O  = 548864;   // cn [1024] f32
// ---- small outputs
constexpr size_t IDX_O = 589824;             // idx [N] i32 (1 MB)
constexpr size_t ESP_O = IDX_O + 1048576;    // es partials [8192] f32
constexpr size_t HP_O  = ESP_O + 32768;      // hist partials [64][1024] i32

__device__ __forceinline__ void split2(float v, _Float16& hi, _Float16& lo) {
  hi = (_Float16)v;
  lo = (_Float16)(v - (float)hi);
}

// =====================================================================
__global__ void prep_kernel(
    const float* __restrict__ ew1, const float* __restrict__ ew2,
    const float* __restrict__ ew3, const float* __restrict__ cb,
    const float* __restrict__ dw1, const float* __restrict__ dw2,
    const float* __restrict__ dw3, char* __restrict__ wsb) {
  _Float16* w1m = (_Float16*)(wsb + W1M_O);
  _Float16* w1r = (_Float16*)(wsb + W1R_O);
  _Float16* e2m = (_Float16*)(wsb + E2M_O);
  _Float16* e2r = (_Float16*)(wsb + E2R_O);
  _Float16* e3m = (_Float16*)(wsb + E3M_O);
  _Float16* e3r = (_Float16*)(wsb + E3R_O);
  _Float16* cbm = (_Float16*)(wsb + CBM_O);
  _Float16* cbr = (_Float16*)(wsb + CBR_O);
  _Float16* d1p = (_Float16*)(wsb + D1P_O);
  _Float16* d2p = (_Float16*)(wsb + D2P_O);
  _Float16* d3p = (_Float16*)(wsb + D3P_O);
  float* cn = (float*)(wsb + CN_O);

  const int gid = blockIdx.x * 256 + threadIdx.x;
  const int stride = gridDim.x * 256;
  for (int e = gid; e < 256 * 32; e += stride) {
    int n = e >> 5, k = e & 31;
    float v = (k < 9) ? ew1[n * 9 + k] : 0.f;
    split2(v, w1m[e], w1r[e]);
  }
  for (int e = gid; e < 128 * 256; e += stride) split2(ew2[e], e2m[e], e2r[e]);
  for (int e = gid; e < 64 * 128; e += stride) split2(ew3[e], e3m[e], e3r[e]);
  for (int e = gid; e < 1024 * 64; e += stride) split2(cb[e], cbm[e], cbr[e]);
  for (int e = gid; e < 128 * 64; e += stride) d1p[e] = (_Float16)dw1[e];
  for (int e = gid; e < 256 * 128; e += stride) d2p[e] = (_Float16)dw2[e];
  for (int e = gid; e < 16 * 256; e += stride) {
    int n = e >> 8, k = e & 255;
    d3p[e] = (n < 9) ? (_Float16)dw3[n * 256 + k] : (_Float16)0.f;
  }
  for (int i = gid; i < 1024; i += stride) {
    float s = 0.f;
    const float* c = cb + (size_t)i * 64;
#pragma unroll 8
    for (int k = 0; k < 64; ++k) s = fmaf(c[k], c[k], s);
    cn[i] = s;
  }
}

// =====================================================================
// Megakernel: 128 rows/block, 4 waves, 2 row-tiles/wave, shared LDS staging.
// LDS: staging 10240 halfs @0 (W2 [128][40]x2 / CB [64][72]x2);
//      wave scratch 2304 halfs/wave @10240+w*2304:
//        A/B/D: [32][36] x2 planes (M@0, R@1152)
//        Z/E:   [16][68] x2 planes (M@0, R@1088); idx[32] i32 @ half-off 2176
__global__ __launch_bounds__(256, 3) void vqvae_mega(
    const float* __restrict__ x,
    const float* __restrict__ eb1, const float* __restrict__ eb2,
    const float* __restrict__ eb3, const float* __restrict__ db1,
    const float* __restrict__ db2, const float* __restrict__ db3,
    const float* __restrict__ cb, const char* __restrict__ wsb,
    float* __restrict__ out, int* __restrict__ idx_g, float* __restrict__ esp_g) {
  __shared__ _Float16 LP[19456];

  const int t = threadIdx.x;
  const int lane = t & 63;
  const int w = t >> 6;
  const int m = lane & 15;
  const int q = lane >> 4;
  const int R0 = blockIdx.x * 128;
  const int wr0 = 32 * w;
  _Float16* WPS = LP + 10240 + w * 2304;
  int* widx = (int*)(WPS + 2176);  // wave-private idx[32]
  const float* cn_g = (const float*)(wsb + CN_O);

  half8 axm[2] = {{}, {}}, axr[2] = {{}, {}};
#pragma unroll
  for (int rt = 0; rt < 2; ++rt) {
    const int grow = R0 + wr0 + 16 * rt + m;
    if (q == 0) {
#pragma unroll
      for (int j = 0; j < 8; ++j) {
        const float v = x[(size_t)grow * 9 + j];
        const _Float16 hi = (_Float16)v;
        axm[rt][j] = hi;
        axr[rt][j] = (_Float16)(v - (float)hi);
      }
    } else if (q == 1) {
      const float v = x[(size_t)grow * 9 + 8];
      const _Float16 hi = (_Float16)v;
      axm[rt][0] = hi;
      axr[rt][0] = (_Float16)(v - (float)hi);
    }
  }

  // ================= Stage A: enc1 fused with enc2 (staged W2 chunks)
  floatx4 acc2[8][2];
#pragma unroll
  for (int nt = 0; nt < 8; ++nt)
#pragma unroll
    for (int rt = 0; rt < 2; ++rt) acc2[nt][rt] = (floatx4){0.f, 0.f, 0.f, 0.f};

  for (int kc = 0; kc < 8; ++kc) {
    __syncthreads();
    {
      const int p = t >> 7, n = t & 127;
      const char* src = wsb + (p ? E2R_O : E2M_O) + (size_t)n * 512 + kc * 64;
      _Float16* dst = LP + (p ? 5120 : 0) + n * 40;
#pragma unroll
      for (int j = 0; j < 4; ++j)
        *(half8*)(dst + j * 8) = *(const half8*)(src + j * 16);
    }
#pragma unroll
    for (int ntl = 0; ntl < 2; ++ntl) {
      const int f = kc * 32 + ntl * 16 + m;
      const half8 bm = *(const half8*)(wsb + W1M_O + (size_t)f * 64 + q * 16);
      const half8 br = *(const half8*)(wsb + W1R_O + (size_t)f * 64 + q * 16);
      const float bias = eb1[f];
#pragma unroll
      for (int rt = 0; rt < 2; ++rt) {
        floatx4 a = (floatx4){0.f, 0.f, 0.f, 0.f};
        a = MFMA16(axr[rt], bm, a);
        a = MFMA16(axm[rt], br, a);
        a = MFMA16(axm[rt], bm, a);
#pragma unroll
        for (int reg = 0; reg < 4; ++reg) {
          const float v = fmaxf(a[reg] + bias, 0.f);
          const int row = 16 * rt + 4 * q + reg;
          const _Float16 hi = (_Float16)v;
          WPS[row * 36 + ntl * 16 + m] = hi;
          WPS[1152 + row * 36 + ntl * 16 + m] = (_Float16)(v - (float)hi);
        }
      }
    }
    __syncthreads();
    half8 am[2], ar[2];
#pragma unroll
    for (int rt = 0; rt < 2; ++rt) {
      am[rt] = *(const half8*)(WPS + (16 * rt + m) * 36 + q * 8);
      ar[rt] = *(const half8*)(WPS + 1152 + (16 * rt + m) * 36 + q * 8);
    }
#pragma unroll
    for (int nt = 0; nt < 8; ++nt) {
      const half8 bm = *(const half8*)(LP + (nt * 16 + m) * 40 + q * 8);
      const half8 br = *(const half8*)(LP + 5120 + (nt * 16 + m) * 40 + q * 8);
#pragma unroll
      for (int rt = 0; rt < 2; ++rt) {
        acc2[nt][rt] = MFMA16(ar[rt], bm, acc2[nt][rt]);
        acc2[nt][rt] = MFMA16(am[rt], br, acc2[nt][rt]);
        acc2[nt][rt] = MFMA16(am[rt], bm, acc2[nt][rt]);
      }
    }
  }

  // ================= Stage B: enc3 (B direct from L2; H2 via wave scratch)
  floatx4 acc3[4][2];
#pragma unroll
  for (int nt = 0; nt < 4; ++nt)
#pragma unroll
    for (int rt = 0; rt < 2; ++rt) acc3[nt][rt] = (floatx4){0.f, 0.f, 0.f, 0.f};

  for (int ks = 0; ks < 4; ++ks) {
#pragma unroll
    for (int h = 0; h < 2; ++h) {
      const int nt = 2 * ks + h;
      const float bias = eb2[nt * 16 + m];
#pragma unroll
      for (int rt = 0; rt < 2; ++rt) {
#pragma unroll
        for (int reg = 0; reg < 4; ++reg) {
          const float v = fmaxf(acc2[nt][rt][reg] + bias, 0.f);
          const int row = 16 * rt + 4 * q + reg;
          const _Float16 hi = (_Float16)v;
          WPS[row * 36 + h * 16 + m] = hi;
          WPS[1152 + row * 36 + h * 16 + m] = (_Float16)(v - (float)hi);
        }
      }
    }
    half8 am[2], ar[2];
#pragma unroll
    for (int rt = 0; rt < 2; ++rt) {
      am[rt] = *(const half8*)(WPS + (16 * rt + m) * 36 + q * 8);
      ar[rt] = *(const half8*)(WPS + 1152 + (16 * rt + m) * 36 + q * 8);
    }
#pragma unroll
    for (int nt = 0; nt < 4; ++nt) {
      const half8 bm = *(const half8*)(wsb + E3M_O + (size_t)(nt * 16 + m) * 256 + ks * 64 + q * 16);
      const half8 br = *(const half8*)(wsb + E3R_O + (size_t)(nt * 16 + m) * 256 + ks * 64 + q * 16);
#pragma unroll
      for (int rt = 0; rt < 2; ++rt) {
        acc3[nt][rt] = MFMA16(ar[rt], bm, acc3[nt][rt]);
        acc3[nt][rt] = MFMA16(am[rt], br, acc3[nt][rt]);
        acc3[nt][rt] = MFMA16(am[rt], bm, acc3[nt][rt]);
      }
    }
  }

  // ---- Z epilogue -> register fragments (no ||z||^2 needed for argmin)
  half8 zfm[2][2], zfr[2][2];
#pragma unroll
  for (int rt = 0; rt < 2; ++rt) {
#pragma unroll
    for (int nt = 0; nt < 4; ++nt) {
      const float bias = eb3[nt * 16 + m];
#pragma unroll
      for (int reg = 0; reg < 4; ++reg) {
        const float v = acc3[nt][rt][reg] + bias;
        const int row = 4 * q + reg;
        const _Float16 hi = (_Float16)v;
        WPS[row * 68 + nt * 16 + m] = hi;
        WPS[1088 + row * 68 + nt * 16 + m] = (_Float16)(v - (float)hi);
      }
    }
#pragma unroll
    for (int ks2 = 0; ks2 < 2; ++ks2) {
      zfm[rt][ks2] = *(const half8*)(WPS + m * 68 + ks2 * 32 + q * 8);
      zfr[rt][ks2] = *(const half8*)(WPS + 1088 + m * 68 + ks2 * 32 + q * 8);
    }
  }

  // ================= Stage C: VQ argmin (staged CB chunks of 64)
  float bestd[2][4];
  int besti[2][4];
#pragma unroll
  for (int rt = 0; rt < 2; ++rt)
#pragma unroll
    for (int reg = 0; reg < 4; ++reg) { bestd[rt][reg] = 3.4e38f; besti[rt][reg] = 0; }

  for (int cc = 0; cc < 16; ++cc) {
    __syncthreads();
    {
      const int p = t >> 7, e = t & 127;
      const int n = e >> 1, hh = e & 1;
      const char* src = wsb + (p ? CBR_O : CBM_O) + (size_t)(cc * 64 + n) * 128 + hh * 64;
      _Float16* dst = LP + (p ? 4608 : 0) + n * 72 + hh * 32;
#pragma unroll
      for (int j = 0; j < 4; ++j)
        *(half8*)(dst + j * 8) = *(const half8*)(src + j * 16);
    }
    __syncthreads();
    floatx4 accd[4][2];
#pragma unroll
    for (int nt = 0; nt < 4; ++nt)
#pragma unroll
      for (int rt = 0; rt < 2; ++rt) accd[nt][rt] = (floatx4){0.f, 0.f, 0.f, 0.f};
#pragma unroll
    for (int nt = 0; nt < 4; ++nt) {
#pragma unroll
      for (int ks2 = 0; ks2 < 2; ++ks2) {
        const half8 bm = *(const half8*)(LP + (nt * 16 + m) * 72 + ks2 * 32 + q * 8);
        const half8 br = *(const half8*)(LP + 4608 + (nt * 16 + m) * 72 + ks2 * 32 + q * 8);
#pragma unroll
        for (int rt = 0; rt < 2; ++rt) {
          accd[nt][rt] = MFMA16(zfr[rt][ks2], bm, accd[nt][rt]);
          accd[nt][rt] = MFMA16(zfm[rt][ks2], br, accd[nt][rt]);
          accd[nt][rt] = MFMA16(zfm[rt][ks2], bm, accd[nt][rt]);
        }
      }
    }
#pragma unroll
    for (int nt = 0; nt < 4; ++nt) {
      const int code = cc * 64 + nt * 16 + m;
      const float cnv = cn_g[code];  // ||z||^2 constant per row -> order-preserving
#pragma unroll
      for (int rt = 0; rt < 2; ++rt) {
#pragma unroll
        for (int reg = 0; reg < 4; ++reg) {
          const float d = cnv - 2.f * accd[nt][rt][reg];
          if (d < bestd[rt][reg]) { bestd[rt][reg] = d; besti[rt][reg] = code; }
        }
      }
    }
  }
#pragma unroll
  for (int rt = 0; rt < 2; ++rt) {
#pragma unroll
    for (int reg = 0; reg < 4; ++reg) {
#pragma unroll
      for (int off = 1; off < 16; off <<= 1) {
        const float od = __shfl_xor(bestd[rt][reg], off, 16);
        const int oi = __shfl_xor(besti[rt][reg], off, 16);
        if (od < bestd[rt][reg] || (od == bestd[rt][reg] && oi < besti[rt][reg])) {
          bestd[rt][reg] = od; besti[rt][reg] = oi;
        }
      }
    }
  }
  if (m == 0) {
#pragma unroll
    for (int rt = 0; rt < 2; ++rt)
#pragma unroll
      for (int reg = 0; reg < 4; ++reg) {
        const int row = 16 * rt + 4 * q + reg;       // wave-local row
        widx[row] = besti[rt][reg];                  // wave-private LDS
        idx_g[R0 + wr0 + row] = besti[rt][reg];      // plain store for hist
      }
  }

  // ---- z_q (straight-through, reference rounding) + per-wave e_latent partial
  half8 zq[2][2];
  float es = 0.f;
#pragma unroll
  for (int rt = 0; rt < 2; ++rt) {
    const int bi = widx[16 * rt + m];  // same-wave LDS read (lgkmcnt ordered)
#pragma unroll
    for (int ks2 = 0; ks2 < 2; ++ks2) {
      const float* cp = cb + (size_t)bi * 64 + ks2 * 32 + q * 8;
      const float4 c0 = *(const float4*)cp;
      const float4 c1 = *(const float4*)(cp + 4);
      float cv[8] = {c0.x, c0.y, c0.z, c0.w, c1.x, c1.y, c1.z, c1.w};
#pragma unroll
      for (int j = 0; j < 8; ++j) {
        const float z = (float)zfm[rt][ks2][j] + (float)zfr[rt][ks2][j];
        const float d = cv[j] - z;
        es = fmaf(d, d, es);
        zq[rt][ks2][j] = (_Float16)(z + d);
      }
    }
  }
#pragma unroll
  for (int off = 1; off < 64; off <<= 1) es += __shfl_xor(es, off, 64);
  if (lane == 0) esp_g[blockIdx.x * 4 + w] = es;  // no atomic

  // ================= Stage D: dec1 (plain fp16, B direct)
  floatx4 accH[8][2];
#pragma unroll
  for (int nt = 0; nt < 8; ++nt)
#pragma unroll
    for (int rt = 0; rt < 2; ++rt) accH[nt][rt] = (floatx4){0.f, 0.f, 0.f, 0.f};
#pragma unroll
  for (int nt = 0; nt < 8; ++nt) {
#pragma unroll
    for (int ks2 = 0; ks2 < 2; ++ks2) {
      const half8 b = *(const half8*)(wsb + D1P_O + (size_t)(nt * 16 + m) * 128 + ks2 * 64 + q * 16);
#pragma unroll
      for (int rt = 0; rt < 2; ++rt) accH[nt][rt] = MFMA16(zq[rt][ks2], b, accH[nt][rt]);
    }
  }
  half8 h3f[2][4];
  for (int ks = 0; ks < 4; ++ks) {
#pragma unroll
    for (int h = 0; h < 2; ++h) {
      const int nt = 2 * ks + h;
      const float bias = db1[nt * 16 + m];
#pragma unroll
      for (int rt = 0; rt < 2; ++rt)
#pragma unroll
        for (int reg = 0; reg < 4; ++reg) {
          const float v = fmaxf(accH[nt][rt][reg] + bias, 0.f);
          WPS[(16 * rt + 4 * q + reg) * 36 + h * 16 + m] = (_Float16)v;
        }
    }
#pragma unroll
    for (int rt = 0; rt < 2; ++rt)
      h3f[rt][ks] = *(const half8*)(WPS + (16 * rt + m) * 36 + q * 8);
  }

  // ================= Stage E: dec2 (staged WD2 chunks) fused with dec3
  floatx4 accO[2] = {(floatx4){0.f, 0.f, 0.f, 0.f}, (floatx4){0.f, 0.f, 0.f, 0.f}};
  for (int jc = 0; jc < 4; ++jc) {
    __syncthreads();
    {
      const int n = t >> 2, jj = t & 3;
      const char* src = wsb + D2P_O + (size_t)(jc * 64 + n) * 256 + jj * 64;
      _Float16* dst = LP + n * 136 + jj * 32;
#pragma unroll
      for (int j = 0; j < 4; ++j)
        *(half8*)(dst + j * 8) = *(const half8*)(src + j * 16);
    }
    __syncthreads();
    floatx4 accD2[4][2];
#pragma unroll
    for (int nt = 0; nt < 4; ++nt)
#pragma unroll
      for (int rt = 0; rt < 2; ++rt) accD2[nt][rt] = (floatx4){0.f, 0.f, 0.f, 0.f};
#pragma unroll
    for (int nt = 0; nt < 4; ++nt) {
#pragma unroll
      for (int ks = 0; ks < 4; ++ks) {
        const half8 b = *(const half8*)(LP + (nt * 16 + m) * 136 + ks * 32 + q * 8);
#pragma unroll
        for (int rt = 0; rt < 2; ++rt) accD2[nt][rt] = MFMA16(h3f[rt][ks], b, accD2[nt][rt]);
      }
    }
    half8 b3[2];
#pragma unroll
    for (int ks2 = 0; ks2 < 2; ++ks2)
      b3[ks2] = *(const half8*)(wsb + D3P_O + (size_t)m * 512 + jc * 128 + ks2 * 64 + q * 16);
#pragma unroll
    for (int rt = 0; rt < 2; ++rt) {
#pragma unroll
      for (int nt = 0; nt < 4; ++nt) {
        const float bias = db2[jc * 64 + nt * 16 + m];
#pragma unroll
        for (int reg = 0; reg < 4; ++reg) {
          const float v = fmaxf(accD2[nt][rt][reg] + bias, 0.f);
          WPS[(4 * q + reg) * 68 + nt * 16 + m] = (_Float16)v;
        }
      }
#pragma unroll
      for (int ks2 = 0; ks2 < 2; ++ks2) {
        const half8 am = *(const half8*)(WPS + m * 68 + ks2 * 32 + q * 8);
        accO[rt] = MFMA16(am, b3[ks2], accO[rt]);
      }
    }
  }
  if (m < 9) {
    const float bias = db3[m];
#pragma unroll
    for (int rt = 0; rt < 2; ++rt)
#pragma unroll
      for (int reg = 0; reg < 4; ++reg) {
        const size_t r = (size_t)(R0 + wr0 + 16 * rt + 4 * q + reg);
        out[r * 9 + m] = accO[rt][reg] + bias;
      }
  }
}

// =====================================================================
__global__ __launch_bounds__(256) void hist_kernel(
    const int* __restrict__ idx_g, int* __restrict__ hp) {
  __shared__ int lh[1024];
  const int t = threadIdx.x;
#pragma unroll
  for (int i = 0; i < 4; ++i) lh[t * 4 + i] = 0;
  __syncthreads();
  for (int i = t; i < 4096; i += 256)
    atomicAdd(&lh[idx_g[blockIdx.x * 4096 + i]], 1);  // LDS atomic only
  __syncthreads();
  int* part = hp + blockIdx.x * 1024;
#pragma unroll
  for (int i = 0; i < 4; ++i) part[t * 4 + i] = lh[t * 4 + i];
}

// =====================================================================
__global__ __launch_bounds__(1024) void finalize_kernel(
    const int* __restrict__ hp, const float* __restrict__ esp,
    float* __restrict__ out2) {
  __shared__ double red[1024];
  __shared__ float rede[1024];
  const int t = threadIdx.x;
  int h = 0;
#pragma unroll 8
  for (int p = 0; p < 64; ++p) h += hp[p * 1024 + t];
  const float pr = (float)h * (1.0f / (float)kN);
  red[t] = (double)(pr * logf(pr + 1e-10f));
  float es = 0.f;
#pragma unroll
  for (int i = 0; i < 8; ++i) es += esp[i * 1024 + t];
  rede[t] = es;
  __syncthreads();
  for (int s = 512; s > 0; s >>= 1) {
    if (t < s) { red[t] += red[t + s]; rede[t] += rede[t + s]; }
    __syncthreads();
  }
  if (t == 0) {
    out2[0] = 1.25f * (rede[0] * (1.0f / ((float)kN * 64.0f)));
    out2[1] = expf((float)(-red[0]));
  }
}

}  // namespace

extern "C" void kernel_launch(void* const* d_in, const int* in_sizes, int n_in,
                              void* d_out, int out_size, void* d_ws, size_t ws_size,
                              hipStream_t stream) {
  const float* x   = (const float*)d_in[0];
  const float* ew1 = (const float*)d_in[1];
  const float* eb1 = (const float*)d_in[2];
  const float* ew2 = (const float*)d_in[3];
  const float* eb2 = (const float*)d_in[4];
  const float* ew3 = (const float*)d_in[5];
  const float* eb3 = (const float*)d_in[6];
  const float* dw1 = (const float*)d_in[7];
  const float* db1 = (const float*)d_in[8];
  const float* dw2 = (const float*)d_in[9];
  const float* db2 = (const float*)d_in[10];
  const float* dw3 = (const float*)d_in[11];
  const float* db3 = (const float*)d_in[12];
  const float* cb  = (const float*)d_in[13];
  float* out = (float*)d_out;
  char* wsb = (char*)d_ws;

  int* idx_g = (int*)(wsb + IDX_O);
  float* esp = (float*)(wsb + ESP_O);
  int* hp = (int*)(wsb + HP_O);

  prep_kernel<<<128, 256, 0, stream>>>(ew1, ew2, ew3, cb, dw1, dw2, dw3, wsb);
  vqvae_mega<<<kN / 128, 256, 0, stream>>>(x, eb1, eb2, eb3, db1, db2, db3, cb,
                                           wsb, out, idx_g, esp);
  hist_kernel<<<64, 256, 0, stream>>>(idx_g, hp);
  finalize_kernel<<<1, 1024, 0, stream>>>(hp, esp, out + (size_t)kN * 9);
}

// Round 13
// 333.657 us; speedup vs baseline: 1.1050x; 1.1050x over previous
//
#include <hip/hip_runtime.h>
#include <math.h>

// VQVAE forward — R13: exact revert to the R10 champion (328us total).
// R10 = R5 shared-staging megakernel (128 rows/block, staged W2/CB/WD2,
// 3 blocks/CU) + R7 no-atomic treatment (idx plain stores, per-wave es
// partials, separate LDS-hist kernel).
// Ledger: R11 (strides 36/68 + LDS diet + bound=4) -> spills, 367us.
//         R12 (bound=3, strides 36/68) -> misaligned half8 LDS gathers
//         (72/136 B not 16B-aligned -> ds_read_b128 split), 369us.
// Lessons: WPS strides must be multiples of 8 halfs; occupancy is
// register-capped (arch 84 + ~64 acc ≈ 148/wave -> 3 waves/SIMD), not LDS.
// Numerics: fp16 split-2 enc+VQ (zero argmin flips R4-R12), plain fp16 dec.

namespace {

constexpr int kN = 262144;

typedef _Float16 half8 __attribute__((ext_vector_type(8)));
typedef float floatx4 __attribute__((ext_vector_type(4)));

#define MFMA16(a, b, c) __builtin_amdgcn_mfma_f32_16x16x32_f16((a), (b), (c), 0, 0, 0)

// ---- workspace byte offsets (weights region, as R4-R12)
constexpr size_t W1M_O = 0;        // ew1 padded [256][32] f16 (k>=9 zero), main
constexpr size_t W1R_O = 16384;    // residual
constexpr size_t E2M_O = 32768;    // ew2 [128][256]
constexpr size_t E2R_O = 98304;
constexpr size_t E3M_O = 163840;   // ew3 [64][128]
constexpr size_t E3R_O = 180224;
constexpr size_t CBM_O = 196608;   // codebook [1024][64]
constexpr size_t CBR_O = 327680;
constexpr size_t D1P_O = 458752;   // dw1 [128][64] plain
constexpr size_t D2P_O = 475136;   // dw2 [256][128] plain
constexpr size_t D3P_O = 540672;   // dw3 padded [16][256] plain
constexpr size_t CN_O  = 548864;   // cn [1024] f32
// ---- small outputs
constexpr size_t IDX_O = 589824;             // idx [N] i32 (1 MB)
constexpr size_t ESP_O = IDX_O + 1048576;    // es partials [8192] f32
constexpr size_t HP_O  = ESP_O + 32768;      // hist partials [64][1024] i32

__device__ __forceinline__ void split2(float v, _Float16& hi, _Float16& lo) {
  hi = (_Float16)v;
  lo = (_Float16)(v - (float)hi);
}

// =====================================================================
__global__ void prep_kernel(
    const float* __restrict__ ew1, const float* __restrict__ ew2,
    const float* __restrict__ ew3, const float* __restrict__ cb,
    const float* __restrict__ dw1, const float* __restrict__ dw2,
    const float* __restrict__ dw3, char* __restrict__ wsb) {
  _Float16* w1m = (_Float16*)(wsb + W1M_O);
  _Float16* w1r = (_Float16*)(wsb + W1R_O);
  _Float16* e2m = (_Float16*)(wsb + E2M_O);
  _Float16* e2r = (_Float16*)(wsb + E2R_O);
  _Float16* e3m = (_Float16*)(wsb + E3M_O);
  _Float16* e3r = (_Float16*)(wsb + E3R_O);
  _Float16* cbm = (_Float16*)(wsb + CBM_O);
  _Float16* cbr = (_Float16*)(wsb + CBR_O);
  _Float16* d1p = (_Float16*)(wsb + D1P_O);
  _Float16* d2p = (_Float16*)(wsb + D2P_O);
  _Float16* d3p = (_Float16*)(wsb + D3P_O);
  float* cn = (float*)(wsb + CN_O);

  const int gid = blockIdx.x * 256 + threadIdx.x;
  const int stride = gridDim.x * 256;
  for (int e = gid; e < 256 * 32; e += stride) {
    int n = e >> 5, k = e & 31;
    float v = (k < 9) ? ew1[n * 9 + k] : 0.f;
    split2(v, w1m[e], w1r[e]);
  }
  for (int e = gid; e < 128 * 256; e += stride) split2(ew2[e], e2m[e], e2r[e]);
  for (int e = gid; e < 64 * 128; e += stride) split2(ew3[e], e3m[e], e3r[e]);
  for (int e = gid; e < 1024 * 64; e += stride) split2(cb[e], cbm[e], cbr[e]);
  for (int e = gid; e < 128 * 64; e += stride) d1p[e] = (_Float16)dw1[e];
  for (int e = gid; e < 256 * 128; e += stride) d2p[e] = (_Float16)dw2[e];
  for (int e = gid; e < 16 * 256; e += stride) {
    int n = e >> 8, k = e & 255;
    d3p[e] = (n < 9) ? (_Float16)dw3[n * 256 + k] : (_Float16)0.f;
  }
  for (int i = gid; i < 1024; i += stride) {
    float s = 0.f;
    const float* c = cb + (size_t)i * 64;
#pragma unroll 8
    for (int k = 0; k < 64; ++k) s = fmaf(c[k], c[k], s);
    cn[i] = s;
  }
}

// =====================================================================
// Megakernel: 128 rows/block, 4 waves, 2 row-tiles/wave, shared LDS staging.
__global__ __launch_bounds__(256, 3) void vqvae_mega(
    const float* __restrict__ x,
    const float* __restrict__ eb1, const float* __restrict__ eb2,
    const float* __restrict__ eb3, const float* __restrict__ db1,
    const float* __restrict__ db2, const float* __restrict__ db3,
    const float* __restrict__ cb, const char* __restrict__ wsb,
    float* __restrict__ out, int* __restrict__ idx_g, float* __restrict__ esp_g) {
  __shared__ _Float16 LP[20480];
  __shared__ int Bidx[128];

  const int t = threadIdx.x;
  const int lane = t & 63;
  const int w = t >> 6;
  const int m = lane & 15;
  const int q = lane >> 4;
  const int R0 = blockIdx.x * 128;
  const int wr0 = 32 * w;
  _Float16* WPS = LP + 10240 + w * 2560;
  const float* cn_g = (const float*)(wsb + CN_O);

  half8 axm[2] = {{}, {}}, axr[2] = {{}, {}};
#pragma unroll
  for (int rt = 0; rt < 2; ++rt) {
    const int grow = R0 + wr0 + 16 * rt + m;
    if (q == 0) {
#pragma unroll
      for (int j = 0; j < 8; ++j) {
        const float v = x[(size_t)grow * 9 + j];
        const _Float16 hi = (_Float16)v;
        axm[rt][j] = hi;
        axr[rt][j] = (_Float16)(v - (float)hi);
      }
    } else if (q == 1) {
      const float v = x[(size_t)grow * 9 + 8];
      const _Float16 hi = (_Float16)v;
      axm[rt][0] = hi;
      axr[rt][0] = (_Float16)(v - (float)hi);
    }
  }

  // ================= Stage A: enc1 fused with enc2 (staged W2 chunks)
  floatx4 acc2[8][2];
#pragma unroll
  for (int nt = 0; nt < 8; ++nt)
#pragma unroll
    for (int rt = 0; rt < 2; ++rt) acc2[nt][rt] = (floatx4){0.f, 0.f, 0.f, 0.f};

  for (int kc = 0; kc < 8; ++kc) {
    __syncthreads();
    {
      const int p = t >> 7, n = t & 127;
      const char* src = wsb + (p ? E2R_O : E2M_O) + (size_t)n * 512 + kc * 64;
      _Float16* dst = LP + (p ? 5120 : 0) + n * 40;
#pragma unroll
      for (int j = 0; j < 4; ++j)
        *(half8*)(dst + j * 8) = *(const half8*)(src + j * 16);
    }
#pragma unroll
    for (int ntl = 0; ntl < 2; ++ntl) {
      const int f = kc * 32 + ntl * 16 + m;
      const half8 bm = *(const half8*)(wsb + W1M_O + (size_t)f * 64 + q * 16);
      const half8 br = *(const half8*)(wsb + W1R_O + (size_t)f * 64 + q * 16);
      const float bias = eb1[f];
#pragma unroll
      for (int rt = 0; rt < 2; ++rt) {
        floatx4 a = (floatx4){0.f, 0.f, 0.f, 0.f};
        a = MFMA16(axr[rt], bm, a);
        a = MFMA16(axm[rt], br, a);
        a = MFMA16(axm[rt], bm, a);
#pragma unroll
        for (int reg = 0; reg < 4; ++reg) {
          const float v = fmaxf(a[reg] + bias, 0.f);
          const int row = 16 * rt + 4 * q + reg;
          const _Float16 hi = (_Float16)v;
          WPS[row * 40 + ntl * 16 + m] = hi;
          WPS[1280 + row * 40 + ntl * 16 + m] = (_Float16)(v - (float)hi);
        }
      }
    }
    __syncthreads();
    half8 am[2], ar[2];
#pragma unroll
    for (int rt = 0; rt < 2; ++rt) {
      am[rt] = *(const half8*)(WPS + (16 * rt + m) * 40 + q * 8);
      ar[rt] = *(const half8*)(WPS + 1280 + (16 * rt + m) * 40 + q * 8);
    }
#pragma unroll
    for (int nt = 0; nt < 8; ++nt) {
      const half8 bm = *(const half8*)(LP + (nt * 16 + m) * 40 + q * 8);
      const half8 br = *(const half8*)(LP + 5120 + (nt * 16 + m) * 40 + q * 8);
#pragma unroll
      for (int rt = 0; rt < 2; ++rt) {
        acc2[nt][rt] = MFMA16(ar[rt], bm, acc2[nt][rt]);
        acc2[nt][rt] = MFMA16(am[rt], br, acc2[nt][rt]);
        acc2[nt][rt] = MFMA16(am[rt], bm, acc2[nt][rt]);
      }
    }
  }

  // ================= Stage B: enc3 (B direct from L2; H2 via wave scratch)
  floatx4 acc3[4][2];
#pragma unroll
  for (int nt = 0; nt < 4; ++nt)
#pragma unroll
    for (int rt = 0; rt < 2; ++rt) acc3[nt][rt] = (floatx4){0.f, 0.f, 0.f, 0.f};

  for (int ks = 0; ks < 4; ++ks) {
#pragma unroll
    for (int h = 0; h < 2; ++h) {
      const int nt = 2 * ks + h;
      const float bias = eb2[nt * 16 + m];
#pragma unroll
      for (int rt = 0; rt < 2; ++rt) {
#pragma unroll
        for (int reg = 0; reg < 4; ++reg) {
          const float v = fmaxf(acc2[nt][rt][reg] + bias, 0.f);
          const int row = 16 * rt + 4 * q + reg;
          const _Float16 hi = (_Float16)v;
          WPS[row * 40 + h * 16 + m] = hi;
          WPS[1280 + row * 40 + h * 16 + m] = (_Float16)(v - (float)hi);
        }
      }
    }
    half8 am[2], ar[2];
#pragma unroll
    for (int rt = 0; rt < 2; ++rt) {
      am[rt] = *(const half8*)(WPS + (16 * rt + m) * 40 + q * 8);
      ar[rt] = *(const half8*)(WPS + 1280 + (16 * rt + m) * 40 + q * 8);
    }
#pragma unroll
    for (int nt = 0; nt < 4; ++nt) {
      const half8 bm = *(const half8*)(wsb + E3M_O + (size_t)(nt * 16 + m) * 256 + ks * 64 + q * 16);
      const half8 br = *(const half8*)(wsb + E3R_O + (size_t)(nt * 16 + m) * 256 + ks * 64 + q * 16);
#pragma unroll
      for (int rt = 0; rt < 2; ++rt) {
        acc3[nt][rt] = MFMA16(ar[rt], bm, acc3[nt][rt]);
        acc3[nt][rt] = MFMA16(am[rt], br, acc3[nt][rt]);
        acc3[nt][rt] = MFMA16(am[rt], bm, acc3[nt][rt]);
      }
    }
  }

  // ---- Z epilogue -> register fragments (no ||z||^2 needed for argmin)
  half8 zfm[2][2], zfr[2][2];
#pragma unroll
  for (int rt = 0; rt < 2; ++rt) {
#pragma unroll
    for (int nt = 0; nt < 4; ++nt) {
      const float bias = eb3[nt * 16 + m];
#pragma unroll
      for (int reg = 0; reg < 4; ++reg) {
        const float v = acc3[nt][rt][reg] + bias;
        const int row = 4 * q + reg;
        const _Float16 hi = (_Float16)v;
        WPS[row * 72 + nt * 16 + m] = hi;
        WPS[1152 + row * 72 + nt * 16 + m] = (_Float16)(v - (float)hi);
      }
    }
#pragma unroll
    for (int ks2 = 0; ks2 < 2; ++ks2) {
      zfm[rt][ks2] = *(const half8*)(WPS + m * 72 + ks2 * 32 + q * 8);
      zfr[rt][ks2] = *(const half8*)(WPS + 1152 + m * 72 + ks2 * 32 + q * 8);
    }
  }

  // ================= Stage C: VQ argmin (staged CB chunks of 64)
  float bestd[2][4];
  int besti[2][4];
#pragma unroll
  for (int rt = 0; rt < 2; ++rt)
#pragma unroll
    for (int reg = 0; reg < 4; ++reg) { bestd[rt][reg] = 3.4e38f; besti[rt][reg] = 0; }

  for (int cc = 0; cc < 16; ++cc) {
    __syncthreads();
    {
      const int p = t >> 7, e = t & 127;
      const int n = e >> 1, hh = e & 1;
      const char* src = wsb + (p ? CBR_O : CBM_O) + (size_t)(cc * 64 + n) * 128 + hh * 64;
      _Float16* dst = LP + (p ? 4608 : 0) + n * 72 + hh * 32;
#pragma unroll
      for (int j = 0; j < 4; ++j)
        *(half8*)(dst + j * 8) = *(const half8*)(src + j * 16);
    }
    __syncthreads();
    floatx4 accd[4][2];
#pragma unroll
    for (int nt = 0; nt < 4; ++nt)
#pragma unroll
      for (int rt = 0; rt < 2; ++rt) accd[nt][rt] = (floatx4){0.f, 0.f, 0.f, 0.f};
#pragma unroll
    for (int nt = 0; nt < 4; ++nt) {
#pragma unroll
      for (int ks2 = 0; ks2 < 2; ++ks2) {
        const half8 bm = *(const half8*)(LP + (nt * 16 + m) * 72 + ks2 * 32 + q * 8);
        const half8 br = *(const half8*)(LP + 4608 + (nt * 16 + m) * 72 + ks2 * 32 + q * 8);
#pragma unroll
        for (int rt = 0; rt < 2; ++rt) {
          accd[nt][rt] = MFMA16(zfr[rt][ks2], bm, accd[nt][rt]);
          accd[nt][rt] = MFMA16(zfm[rt][ks2], br, accd[nt][rt]);
          accd[nt][rt] = MFMA16(zfm[rt][ks2], bm, accd[nt][rt]);
        }
      }
    }
#pragma unroll
    for (int nt = 0; nt < 4; ++nt) {
      const int code = cc * 64 + nt * 16 + m;
      const float cnv = cn_g[code];  // ||z||^2 constant per row -> order-preserving
#pragma unroll
      for (int rt = 0; rt < 2; ++rt) {
#pragma unroll
        for (int reg = 0; reg < 4; ++reg) {
          const float d = cnv - 2.f * accd[nt][rt][reg];
          if (d < bestd[rt][reg]) { bestd[rt][reg] = d; besti[rt][reg] = code; }
        }
      }
    }
  }
#pragma unroll
  for (int rt = 0; rt < 2; ++rt) {
#pragma unroll
    for (int reg = 0; reg < 4; ++reg) {
#pragma unroll
      for (int off = 1; off < 16; off <<= 1) {
        const float od = __shfl_xor(bestd[rt][reg], off, 16);
        const int oi = __shfl_xor(besti[rt][reg], off, 16);
        if (od < bestd[rt][reg] || (od == bestd[rt][reg] && oi < besti[rt][reg])) {
          bestd[rt][reg] = od; besti[rt][reg] = oi;
        }
      }
    }
  }
  if (m == 0) {
#pragma unroll
    for (int rt = 0; rt < 2; ++rt)
#pragma unroll
      for (int reg = 0; reg < 4; ++reg) {
        const int row = wr0 + 16 * rt + 4 * q + reg;
        Bidx[row] = besti[rt][reg];        // same-wave LDS use only
        idx_g[R0 + row] = besti[rt][reg];  // plain store; hist kernel follows
      }
  }

  // ---- z_q (straight-through, reference rounding) + per-wave e_latent partial
  half8 zq[2][2];
  float es = 0.f;
#pragma unroll
  for (int rt = 0; rt < 2; ++rt) {
    const int bi = Bidx[wr0 + 16 * rt + m];
#pragma unroll
    for (int ks2 = 0; ks2 < 2; ++ks2) {
      const float* cp = cb + (size_t)bi * 64 + ks2 * 32 + q * 8;
      const float4 c0 = *(const float4*)cp;
      const float4 c1 = *(const float4*)(cp + 4);
      float cv[8] = {c0.x, c0.y, c0.z, c0.w, c1.x, c1.y, c1.z, c1.w};
#pragma unroll
      for (int j = 0; j < 8; ++j) {
        const float z = (float)zfm[rt][ks2][j] + (float)zfr[rt][ks2][j];
        const float d = cv[j] - z;
        es = fmaf(d, d, es);
        zq[rt][ks2][j] = (_Float16)(z + d);
      }
    }
  }
#pragma unroll
  for (int off = 1; off < 64; off <<= 1) es += __shfl_xor(es, off, 64);
  if (lane == 0) esp_g[blockIdx.x * 4 + w] = es;  // no atomic

  // ================= Stage D: dec1 (plain fp16, B direct)
  floatx4 accH[8][2];
#pragma unroll
  for (int nt = 0; nt < 8; ++nt)
#pragma unroll
    for (int rt = 0; rt < 2; ++rt) accH[nt][rt] = (floatx4){0.f, 0.f, 0.f, 0.f};
#pragma unroll
  for (int nt = 0; nt < 8; ++nt) {
#pragma unroll
    for (int ks2 = 0; ks2 < 2; ++ks2) {
      const half8 b = *(const half8*)(wsb + D1P_O + (size_t)(nt * 16 + m) * 128 + ks2 * 64 + q * 16);
#pragma unroll
      for (int rt = 0; rt < 2; ++rt) accH[nt][rt] = MFMA16(zq[rt][ks2], b, accH[nt][rt]);
    }
  }
  half8 h3f[2][4];
  for (int ks = 0; ks < 4; ++ks) {
#pragma unroll
    for (int h = 0; h < 2; ++h) {
      const int nt = 2 * ks + h;
      const float bias = db1[nt * 16 + m];
#pragma unroll
      for (int rt = 0; rt < 2; ++rt)
#pragma unroll
        for (int reg = 0; reg < 4; ++reg) {
          const float v = fmaxf(accH[nt][rt][reg] + bias, 0.f);
          WPS[(16 * rt + 4 * q + reg) * 40 + h * 16 + m] = (_Float16)v;
        }
    }
#pragma unroll
    for (int rt = 0; rt < 2; ++rt)
      h3f[rt][ks] = *(const half8*)(WPS + (16 * rt + m) * 40 + q * 8);
  }

  // ================= Stage E: dec2 (staged WD2 chunks) fused with dec3
  floatx4 accO[2] = {(floatx4){0.f, 0.f, 0.f, 0.f}, (floatx4){0.f, 0.f, 0.f, 0.f}};
  for (int jc = 0; jc < 4; ++jc) {
    __syncthreads();
    {
      const int n = t >> 2, jj = t & 3;
      const char* src = wsb + D2P_O + (size_t)(jc * 64 + n) * 256 + jj * 64;
      _Float16* dst = LP + n * 136 + jj * 32;
#pragma unroll
      for (int j = 0; j < 4; ++j)
        *(half8*)(dst + j * 8) = *(const half8*)(src + j * 16);
    }
    __syncthreads();
    floatx4 accD2[4][2];
#pragma unroll
    for (int nt = 0; nt < 4; ++nt)
#pragma unroll
      for (int rt = 0; rt < 2; ++rt) accD2[nt][rt] = (floatx4){0.f, 0.f, 0.f, 0.f};
#pragma unroll
    for (int nt = 0; nt < 4; ++nt) {
#pragma unroll
      for (int ks = 0; ks < 4; ++ks) {
        const half8 b = *(const half8*)(LP + (nt * 16 + m) * 136 + ks * 32 + q * 8);
#pragma unroll
        for (int rt = 0; rt < 2; ++rt) accD2[nt][rt] = MFMA16(h3f[rt][ks], b, accD2[nt][rt]);
      }
    }
    half8 b3[2];
#pragma unroll
    for (int ks2 = 0; ks2 < 2; ++ks2)
      b3[ks2] = *(const half8*)(wsb + D3P_O + (size_t)m * 512 + jc * 128 + ks2 * 64 + q * 16);
#pragma unroll
    for (int rt = 0; rt < 2; ++rt) {
#pragma unroll
      for (int nt = 0; nt < 4; ++nt) {
        const float bias = db2[jc * 64 + nt * 16 + m];
#pragma unroll
        for (int reg = 0; reg < 4; ++reg) {
          const float v = fmaxf(accD2[nt][rt][reg] + bias, 0.f);
          WPS[(4 * q + reg) * 72 + nt * 16 + m] = (_Float16)v;
        }
      }
#pragma unroll
      for (int ks2 = 0; ks2 < 2; ++ks2) {
        const half8 am = *(const half8*)(WPS + m * 72 + ks2 * 32 + q * 8);
        accO[rt] = MFMA16(am, b3[ks2], accO[rt]);
      }
    }
  }
  if (m < 9) {
    const float bias = db3[m];
#pragma unroll
    for (int rt = 0; rt < 2; ++rt)
#pragma unroll
      for (int reg = 0; reg < 4; ++reg) {
        const size_t r = (size_t)(R0 + wr0 + 16 * rt + 4 * q + reg);
        out[r * 9 + m] = accO[rt][reg] + bias;
      }
  }
}

// =====================================================================
__global__ __launch_bounds__(256) void hist_kernel(
    const int* __restrict__ idx_g, int* __restrict__ hp) {
  __shared__ int lh[1024];
  const int t = threadIdx.x;
#pragma unroll
  for (int i = 0; i < 4; ++i) lh[t * 4 + i] = 0;
  __syncthreads();
  for (int i = t; i < 4096; i += 256)
    atomicAdd(&lh[idx_g[blockIdx.x * 4096 + i]], 1);  // LDS atomic only
  __syncthreads();
  int* part = hp + blockIdx.x * 1024;
#pragma unroll
  for (int i = 0; i < 4; ++i) part[t * 4 + i] = lh[t * 4 + i];
}

// =====================================================================
__global__ __launch_bounds__(1024) void finalize_kernel(
    const int* __restrict__ hp, const float* __restrict__ esp,
    float* __restrict__ out2) {
  __shared__ double red[1024];
  __shared__ float rede[1024];
  const int t = threadIdx.x;
  int h = 0;
#pragma unroll 8
  for (int p = 0; p < 64; ++p) h += hp[p * 1024 + t];
  const float pr = (float)h * (1.0f / (float)kN);
  red[t] = (double)(pr * logf(pr + 1e-10f));
  float es = 0.f;
#pragma unroll
  for (int i = 0; i < 8; ++i) es += esp[i * 1024 + t];
  rede[t] = es;
  __syncthreads();
  for (int s = 512; s > 0; s >>= 1) {
    if (t < s) { red[t] += red[t + s]; rede[t] += rede[t + s]; }
    __syncthreads();
  }
  if (t == 0) {
    out2[0] = 1.25f * (rede[0] * (1.0f / ((float)kN * 64.0f)));
    out2[1] = expf((float)(-red[0]));
  }
}

}  // namespace

extern "C" void kernel_launch(void* const* d_in, const int* in_sizes, int n_in,
                              void* d_out, int out_size, void* d_ws, size_t ws_size,
                              hipStream_t stream) {
  const float* x   = (const float*)d_in[0];
  const float* ew1 = (const float*)d_in[1];
  const float* eb1 = (const float*)d_in[2];
  const float* ew2 = (const float*)d_in[3];
  const float* eb2 = (const float*)d_in[4];
  const float* ew3 = (const float*)d_in[5];
  const float* eb3 = (const float*)d_in[6];
  const float* dw1 = (const float*)d_in[7];
  const float* db1 = (const float*)d_in[8];
  const float* dw2 = (const float*)d_in[9];
  const float* db2 = (const float*)d_in[10];
  const float* dw3 = (const float*)d_in[11];
  const float* db3 = (const float*)d_in[12];
  const float* cb  = (const float*)d_in[13];
  float* out = (float*)d_out;
  char* wsb = (char*)d_ws;

  int* idx_g = (int*)(wsb + IDX_O);
  float* esp = (float*)(wsb + ESP_O);
  int* hp = (int*)(wsb + HP_O);

  prep_kernel<<<128, 256, 0, stream>>>(ew1, ew2, ew3, cb, dw1, dw2, dw3, wsb);
  vqvae_mega<<<kN / 128, 256, 0, stream>>>(x, eb1, eb2, eb3, db1, db2, db3, cb,
                                           wsb, out, idx_g, esp);
  hist_kernel<<<64, 256, 0, stream>>>(idx_g, hp);
  finalize_kernel<<<1, 1024, 0, stream>>>(hp, esp, out + (size_t)kN * 9);
}